// Round 8
// baseline (78557.434 us; speedup 1.0000x reference)
//
#include <hip/hip_runtime.h>

constexpr int TT = 2048;   // timesteps
constexpr int NB = 128;    // batch
constexpr int NI = 64;     // input size
constexpr int NH = 256;    // hidden
constexpr int NWG  = 256;  // 128 layer-0 + 128 layer-1 WGs
constexpr int NTHR = 512;
constexpr int NGR  = 16;   // independent batch groups (8 b each)
constexpr int R0   = 8;    // h0 ring slots
constexpr int R1   = 2;    // h1 ring slots
constexpr int SLOT = NGR * 128 * 8;   // dwords per ring slot ([grp][kp][b])

typedef _Float16 half2_t __attribute__((ext_vector_type(2)));

// Per-(layer,group) monotone counters, one cacheline apart. Zero at load;
// reset at kernel end -> graph-replay safe.
__device__ unsigned g_c0[NGR * 32];
__device__ unsigned g_c1[NGR * 32];
__device__ unsigned g_cnt = 0, g_gen = 0;

__device__ __forceinline__ float sigm(float v) { return 1.0f / (1.0f + __expf(-v)); }
__device__ __forceinline__ float tanhfast(float v) {
    float e = __expf(2.0f * v);
    return 1.0f - 2.0f / (e + 1.0f);
}
__device__ __forceinline__ unsigned packh(float a, float b) {
    unsigned short ua = __builtin_bit_cast(unsigned short, (_Float16)a);
    unsigned short ub = __builtin_bit_cast(unsigned short, (_Float16)b);
    return ((unsigned)ub << 16) | ua;
}
// fp16 pair dot with fp32 accumulate: 2 MACs / instruction on CDNA.
__device__ __forceinline__ float dot2u(unsigned a, unsigned b, float c) {
#if __has_builtin(__builtin_amdgcn_fdot2)
    return __builtin_amdgcn_fdot2(__builtin_bit_cast(half2_t, a),
                                  __builtin_bit_cast(half2_t, b), c, false);
#else
    half2_t ha = __builtin_bit_cast(half2_t, a);
    half2_t hb = __builtin_bit_cast(half2_t, b);
    return c + (float)ha.x * (float)hb.x + (float)ha.y * (float)hb.y;
#endif
}

// LLC-coherent (agent-scope relaxed) accessors for cross-WG data.
__device__ __forceinline__ unsigned ldd(const unsigned* p) {
    return __hip_atomic_load(p, __ATOMIC_RELAXED, __HIP_MEMORY_SCOPE_AGENT);
}
__device__ __forceinline__ void std_(unsigned* p, unsigned v) {
    __hip_atomic_store(p, v, __ATOMIC_RELAXED, __HIP_MEMORY_SCOPE_AGENT);
}
__device__ __forceinline__ void bump(unsigned* p) {
    (void)__hip_atomic_fetch_add(p, 1u, __ATOMIC_RELAXED, __HIP_MEMORY_SCOPE_AGENT);
}
// One combined wait: lane0 polls line A, lane1 polls line B (1 load/round).
__device__ __forceinline__ void waitge2(const unsigned* pa, unsigned ta,
                                        const unsigned* pb, unsigned tb, int lane) {
    const unsigned* p = (lane & 1) ? pb : pa;
    for (;;) {
        unsigned v = ldd(p);
        unsigned va = (unsigned)__shfl((int)v, 0);
        unsigned vb = (unsigned)__shfl((int)v, 1);
        if ((int)(va - ta) >= 0 && (int)(vb - tb) >= 0) return;
        __builtin_amdgcn_s_sleep(1);
    }
}

// Counter barrier, ONLY for the end-of-kernel reset protocol.
__device__ __forceinline__ void gridbar(unsigned k, bool last) {
    __syncthreads();
    if (threadIdx.x == 0) {
        __threadfence();
        unsigned a = __hip_atomic_fetch_add(&g_cnt, 1u, __ATOMIC_ACQ_REL,
                                            __HIP_MEMORY_SCOPE_AGENT);
        if (a == k * NWG - 1u) {
            if (last) {
                __hip_atomic_store(&g_cnt, 0u, __ATOMIC_RELAXED, __HIP_MEMORY_SCOPE_AGENT);
                __hip_atomic_store(&g_gen, 0u, __ATOMIC_RELEASE, __HIP_MEMORY_SCOPE_AGENT);
            } else {
                __hip_atomic_store(&g_gen, k, __ATOMIC_RELEASE, __HIP_MEMORY_SCOPE_AGENT);
            }
        } else if (!last) {
            while (__hip_atomic_load(&g_gen, __ATOMIC_RELAXED,
                                     __HIP_MEMORY_SCOPE_AGENT) < k)
                __builtin_amdgcn_s_sleep(1);
        }
        __threadfence();
    }
    __syncthreads();
}

// 4-gate partial dot over a 128-k half of one fp16 matrix (row pitch 128
// dwords) against fp16-packed h ([kp][8b] dwords, LLC-bypass loads).
__device__ __forceinline__ void dotf16(const unsigned* __restrict__ wbase,
                                       int jglob, int kh,
                                       const unsigned* __restrict__ hring,
                                       int b, float* acc) {
    const unsigned* w0 = wbase + (size_t)(0 * NH + jglob) * 128 + kh * 64;
    const unsigned* w1 = wbase + (size_t)(1 * NH + jglob) * 128 + kh * 64;
    const unsigned* w2 = wbase + (size_t)(2 * NH + jglob) * 128 + kh * 64;
    const unsigned* w3 = wbase + (size_t)(3 * NH + jglob) * 128 + kh * 64;
    const unsigned* hp = hring + (size_t)(kh * 64) * 8 + b;
    #pragma unroll
    for (int i = 0; i < 16; ++i) {
        uint4 a0 = *(const uint4*)(w0 + i * 4);
        uint4 a1 = *(const uint4*)(w1 + i * 4);
        uint4 a2 = *(const uint4*)(w2 + i * 4);
        uint4 a3 = *(const uint4*)(w3 + i * 4);
        unsigned h0 = ldd(hp + (size_t)(i * 4 + 0) * 8);
        unsigned h1 = ldd(hp + (size_t)(i * 4 + 1) * 8);
        unsigned h2 = ldd(hp + (size_t)(i * 4 + 2) * 8);
        unsigned h3 = ldd(hp + (size_t)(i * 4 + 3) * 8);
        acc[0] = dot2u(a0.x, h0, acc[0]); acc[0] = dot2u(a0.y, h1, acc[0]);
        acc[0] = dot2u(a0.z, h2, acc[0]); acc[0] = dot2u(a0.w, h3, acc[0]);
        acc[1] = dot2u(a1.x, h0, acc[1]); acc[1] = dot2u(a1.y, h1, acc[1]);
        acc[1] = dot2u(a1.z, h2, acc[1]); acc[1] = dot2u(a1.w, h3, acc[1]);
        acc[2] = dot2u(a2.x, h0, acc[2]); acc[2] = dot2u(a2.y, h1, acc[2]);
        acc[2] = dot2u(a2.z, h2, acc[2]); acc[2] = dot2u(a2.w, h3, acc[2]);
        acc[3] = dot2u(a3.x, h0, acc[3]); acc[3] = dot2u(a3.y, h1, acc[3]);
        acc[3] = dot2u(a3.z, h2, acc[3]); acc[3] = dot2u(a3.w, h3, acc[3]);
    }
}

// 4-gate partial dot over a 32-k half of fp32 Wih0 against fp32 x row.
__device__ __forceinline__ void dotx(const float* __restrict__ W, int jglob,
                                     int kh, const float* __restrict__ xr,
                                     float* acc) {
    const float* w0 = W + (size_t)(0 * NH + jglob) * NI + kh * 32;
    const float* w1 = W + (size_t)(1 * NH + jglob) * NI + kh * 32;
    const float* w2 = W + (size_t)(2 * NH + jglob) * NI + kh * 32;
    const float* w3 = W + (size_t)(3 * NH + jglob) * NI + kh * 32;
    const float* xp = xr + kh * 32;
    #pragma unroll
    for (int i = 0; i < 8; ++i) {
        float4 xv = *(const float4*)(xp + i * 4);
        float4 a0 = *(const float4*)(w0 + i * 4);
        float4 a1 = *(const float4*)(w1 + i * 4);
        float4 a2 = *(const float4*)(w2 + i * 4);
        float4 a3 = *(const float4*)(w3 + i * 4);
        acc[0] += a0.x*xv.x + a0.y*xv.y + a0.z*xv.z + a0.w*xv.w;
        acc[1] += a1.x*xv.x + a1.y*xv.y + a1.z*xv.z + a1.w*xv.w;
        acc[2] += a2.x*xv.x + a2.y*xv.y + a2.z*xv.z + a2.w*xv.w;
        acc[3] += a3.x*xv.x + a3.y*xv.y + a3.z*xv.z + a3.w*xv.w;
    }
}

// Prep kernel: fp32->fp16 weight conversion (Whh0, Wih1, Whh1, elementwise,
// layout preserved) + zero the atomically-accumulated output.
__global__ void prep(const float* __restrict__ wh0, const float* __restrict__ wi1,
                     const float* __restrict__ wh1, unsigned short* __restrict__ dst,
                     float* __restrict__ out) {
    const size_t n = (size_t)4 * NH * NH;          // 262144 per matrix
    const size_t stride = (size_t)gridDim.x * blockDim.x;
    for (size_t i = (size_t)blockIdx.x * blockDim.x + threadIdx.x;
         i < 3 * n; i += stride) {
        const float* src = (i < n) ? wh0 : (i < 2 * n ? wi1 : wh1);
        size_t off = (i < n) ? i : (i < 2 * n ? i - n : i - 2 * n);
        dst[i] = __builtin_bit_cast(unsigned short, (_Float16)src[off]);
    }
    for (size_t i = (size_t)blockIdx.x * blockDim.x + threadIdx.x;
         i < (size_t)TT * NB; i += stride)
        out[i] = 0.0f;
}

// Grid: 256 WGs x 512 thr. gid<128: layer 0; else layer 1 (+head).
// WG (grp, jgrp): batch slice [8*grp, 8*grp+8), j rows [32*jgrp, 32*jgrp+32).
// Thread tid = kh*256 + j*8 + b: computes 4 gates for (j,b) over its 128-k
// half (both matrices); halves meet in LDS zp. c in registers (kh==0 threads).
// Groups are fully independent; within a group, fan-in is 8 WGs via one
// counter line per (layer,group). Head: L1 WGs own h1 -> in-register Wlin
// partials, shuffle-reduce, 8 atomicAdds per WG per step (off critical path).
__global__ void __launch_bounds__(NTHR, 2) lstm2(
    const float* __restrict__ x,
    const float* __restrict__ h0in, const float* __restrict__ c0in,
    const float* __restrict__ Wih0,
    const float* __restrict__ bih0, const float* __restrict__ bhh0,
    const float* __restrict__ bih1, const float* __restrict__ bhh1,
    const float* __restrict__ Wlin, const float* __restrict__ blin,
    float* __restrict__ out,
    const unsigned* __restrict__ wh0h, const unsigned* __restrict__ wi1h,
    const unsigned* __restrict__ wh1h,
    unsigned* __restrict__ ring0, unsigned* __restrict__ ring1)
{
    __shared__ __align__(16) float4 zp[256];   // partner-half gate partials, 4 KB
    __shared__ float lh[4][8];                 // head wave partials

    const int tid  = threadIdx.x;
    const int gid  = blockIdx.x;
    const bool is1 = gid >= 128;
    const int lgid = is1 ? gid - 128 : gid;
    const int grp  = lgid >> 3;
    const int jgrp = lgid & 7;
    const int lane = tid & 63;
    const int wv   = tid >> 6;
    const int cj   = (tid >> 3) & 31;      // j within slice
    const int cb   = tid & 7;              // b within group
    const int kh   = tid >> 8;             // k half
    const int jglob = jgrp * 32 + cj;
    const int bglob = grp * 8 + cb;

    unsigned* ownl = (is1 ? g_c1 : g_c0) + grp * 32;
    unsigned* crsl = (is1 ? g_c0 : g_c1) + grp * 32;

    // ---- init: biases, c, Wlin; publish h(-1) ----
    float bs0 = 0, bs1 = 0, bs2 = 0, bs3 = 0, cC = 0, wl = 0;
    if (kh == 0) {
        const float* bi = is1 ? bih1 : bih0;
        const float* bh = is1 ? bhh1 : bhh0;
        bs0 = bi[0 * NH + jglob] + bh[0 * NH + jglob];
        bs1 = bi[1 * NH + jglob] + bh[1 * NH + jglob];
        bs2 = bi[2 * NH + jglob] + bh[2 * NH + jglob];
        bs3 = bi[3 * NH + jglob] + bh[3 * NH + jglob];
        cC = c0in[(is1 ? 1 : 0) * NB * NH + (size_t)bglob * NH + jglob];
        wl = Wlin[jglob];
        if ((cj & 1) == 0) {
            const float* hb = h0in + (is1 ? 1 : 0) * NB * NH + (size_t)bglob * NH;
            unsigned* ring = is1 ? ring1 : ring0;
            const int islot = is1 ? (R1 - 1) : (R0 - 1);
            std_(ring + (size_t)(islot * NGR + grp) * 1024 + (size_t)(jglob >> 1) * 8 + cb,
                 packh(hb[jglob], hb[jglob + 1]));
        }
    }
    const float blv = blin[0];
    asm volatile("s_waitcnt vmcnt(0)" ::: "memory");
    __syncthreads();
    if (tid == 0) bump(ownl);   // group counter -> 8 after init

    if (!is1) {
        // ================= layer 0 =================
        for (int s = 0; s < TT; ++s) {
            // own: h0(s-1) ready (cnt >= 8(s+1)); cross: ring-overwrite guard
            // (L1 consumed h0(s-8): cnt1 >= 8(s-6), active s>=8).
            unsigned t1 = (s >= 8) ? 8u * (unsigned)(s - 6) : 0u;
            waitge2(ownl, 8u * (unsigned)(s + 1), crsl, t1, lane);

            float acc[4] = {0, 0, 0, 0};
            dotf16(wh0h, jglob, kh,
                   ring0 + (size_t)(((s + R0 - 1) & (R0 - 1)) * NGR + grp) * 1024,
                   cb, acc);
            dotx(Wih0, jglob, kh, x + ((size_t)s * NB + bglob) * NI, acc);

            if (kh == 1) zp[tid - 256] = make_float4(acc[0], acc[1], acc[2], acc[3]);
            __syncthreads();
            if (kh == 0) {
                float4 o = zp[tid];
                float z0 = acc[0] + o.x + bs0, z1 = acc[1] + o.y + bs1;
                float z2 = acc[2] + o.z + bs2, z3 = acc[3] + o.w + bs3;
                float ig = sigm(z0), fg = sigm(z1), gg = tanhfast(z2), og = sigm(z3);
                cC = fg * cC + ig * gg;
                float hn = og * tanhfast(cC);
                float hx = __shfl_down(hn, 8);
                if ((cj & 1) == 0)
                    std_(ring0 + (size_t)((s & (R0 - 1)) * NGR + grp) * 1024
                         + (size_t)(jglob >> 1) * 8 + cb, packh(hn, hx));
            }
            asm volatile("s_waitcnt vmcnt(0)" ::: "memory");
            __syncthreads();
            if (tid == 0) bump(ownl);
        }
    } else {
        // ================= layer 1 (+ head) =================
        for (int t = 0; t < TT; ++t) {
            // own: h1(t-1) (cnt1 >= 8(t+1)); cross: h0(t) (cnt0 >= 8(t+2)).
            waitge2(ownl, 8u * (unsigned)(t + 1), crsl, 8u * (unsigned)(t + 2), lane);

            float acc[4] = {0, 0, 0, 0};
            dotf16(wi1h, jglob, kh,
                   ring0 + (size_t)((t & (R0 - 1)) * NGR + grp) * 1024, cb, acc);
            dotf16(wh1h, jglob, kh,
                   ring1 + (size_t)(((t + 1) & 1) * NGR + grp) * 1024, cb, acc);

            if (kh == 1) zp[tid - 256] = make_float4(acc[0], acc[1], acc[2], acc[3]);
            __syncthreads();
            float p = 0.0f;
            if (kh == 0) {
                float4 o = zp[tid];
                float z0 = acc[0] + o.x + bs0, z1 = acc[1] + o.y + bs1;
                float z2 = acc[2] + o.z + bs2, z3 = acc[3] + o.w + bs3;
                float ig = sigm(z0), fg = sigm(z1), gg = tanhfast(z2), og = sigm(z3);
                cC = fg * cC + ig * gg;
                float hn = og * tanhfast(cC);
                float hx = __shfl_down(hn, 8);
                if ((cj & 1) == 0)
                    std_(ring1 + (size_t)((t & 1) * NGR + grp) * 1024
                         + (size_t)(jglob >> 1) * 8 + cb, packh(hn, hx));
                p = wl * hn;
                p += __shfl_xor(p, 8);
                p += __shfl_xor(p, 16);
                p += __shfl_xor(p, 32);
            }
            asm volatile("s_waitcnt vmcnt(0)" ::: "memory");
            __syncthreads();
            if (tid == 0) bump(ownl);

            // head (off critical path, after publish+bump)
            if (kh == 0 && lane < 8) lh[wv][lane] = p;
            __syncthreads();
            if (tid < 8) {
                float sum = lh[0][tid] + lh[1][tid] + lh[2][tid] + lh[3][tid]
                          + (jgrp == 0 ? blv : 0.0f);
                atomicAdd(&out[(size_t)t * NB + grp * 8 + tid], sum);
            }
        }
    }

    // ---- end protocol: reset counters behind a real barrier (replay-safe) ----
    gridbar(1, false);
    if (gid == 0) {
        if (tid < NGR)
            __hip_atomic_store(&g_c0[tid * 32], 0u, __ATOMIC_RELAXED,
                               __HIP_MEMORY_SCOPE_AGENT);
        else if (tid < 2 * NGR)
            __hip_atomic_store(&g_c1[(tid - NGR) * 32], 0u, __ATOMIC_RELAXED,
                               __HIP_MEMORY_SCOPE_AGENT);
    }
    gridbar(2, true);
}

extern "C" void kernel_launch(void* const* d_in, const int* in_sizes, int n_in,
                              void* d_out, int out_size, void* d_ws, size_t ws_size,
                              hipStream_t stream)
{
    const float* x    = (const float*)d_in[0];
    const float* h0in = (const float*)d_in[1];
    const float* c0in = (const float*)d_in[2];
    const float* Wih0 = (const float*)d_in[3];
    const float* Whh0 = (const float*)d_in[4];
    const float* bih0 = (const float*)d_in[5];
    const float* bhh0 = (const float*)d_in[6];
    const float* Wih1 = (const float*)d_in[7];
    const float* Whh1 = (const float*)d_in[8];
    const float* bih1 = (const float*)d_in[9];
    const float* bhh1 = (const float*)d_in[10];
    const float* Wlin = (const float*)d_in[11];
    const float* blin = (const float*)d_in[12];
    float* out = (float*)d_out;

    // ws layout: [fp16 weights: Whh0|Wih1|Whh1, 3x256KB] [ring0 512KB] [ring1 128KB]
    unsigned short* wf = (unsigned short*)d_ws;
    const unsigned* wh0h = (const unsigned*)wf;
    const unsigned* wi1h = wh0h + 131072;
    const unsigned* wh1h = wi1h + 131072;
    unsigned* ring0 = (unsigned*)(wf + 3 * 262144);
    unsigned* ring1 = ring0 + (size_t)R0 * SLOT;

    prep<<<1024, 256, 0, stream>>>(Whh0, Wih1, Whh1, wf, out);

    void* args[] = { &x, &h0in, &c0in, &Wih0, &bih0, &bhh0, &bih1, &bhh1,
                     &Wlin, &blin, &out,
                     &wh0h, &wi1h, &wh1h, &ring0, &ring1 };
    hipLaunchCooperativeKernel((void*)lstm2, dim3(NWG), dim3(NTHR), args, 0, stream);
}